// Round 6
// baseline (485.868 us; speedup 1.0000x reference)
//
#include <hip/hip_runtime.h>
#include <hip/hip_bf16.h>

#define NATC  1024
#define BATCH 4
#define MNTC  200
#define M1C   100
#define M2C   16
#define FHC   240
#define KPAD  256
#define HSTR  264   // fitm LDS h row stride (bf16): 528B rows
#define H1STR 40    // embed h1 stage stride (bf16): 80B rows
#define H2STR 72    // embed h2 stage stride (bf16): 144B rows

typedef __attribute__((ext_vector_type(8))) short bf16x8;
typedef __attribute__((ext_vector_type(4))) float f32x4;

__device__ __forceinline__ float fast_tanh(float x){
    float e = __expf(2.0f * x);
    float r = __fdividef(1.0f, e + 1.0f);
    return fmaf(-2.0f, r, 1.0f);
}

__device__ __forceinline__ unsigned short f2bf(float x){
    __hip_bfloat16 h = __float2bfloat16(x);
    return *reinterpret_cast<unsigned short*>(&h);
}

__device__ __forceinline__ float bf2f(unsigned short u){
    unsigned int v = ((unsigned int)u) << 16;
    return *reinterpret_cast<float*>(&v);
}

__device__ __forceinline__ unsigned int pack2(float a, float b){
    return (unsigned int)f2bf(a) | ((unsigned int)f2bf(b) << 16);
}

// ---------------- partition atoms by type (deterministic) ----------------
__global__ __launch_bounds__(256) void part_kernel(const int* __restrict__ tmap,
                                                   int* __restrict__ idx,
                                                   int* __restrict__ counts){
    __shared__ int s0[256], s1[256];
    const int tid = threadIdx.x;
    int ty[4]; int c0 = 0, c1 = 0;
    #pragma unroll
    for (int r = 0; r < 4; ++r){
        ty[r] = tmap[tid*4 + r];
        if (ty[r] == 0) c0++; else c1++;
    }
    s0[tid] = c0; s1[tid] = c1;
    __syncthreads();
    for (int off = 1; off < 256; off <<= 1){
        int v0 = (tid >= off) ? s0[tid-off] : 0;
        int v1 = (tid >= off) ? s1[tid-off] : 0;
        __syncthreads();
        s0[tid] += v0; s1[tid] += v1;
        __syncthreads();
    }
    int e0 = s0[tid] - c0, e1 = s1[tid] - c1;
    #pragma unroll
    for (int r = 0; r < 4; ++r){
        int n = tid*4 + r;
        if (ty[r] == 0) idx[e0++] = n; else idx[NATC + e1++] = n;
    }
    if (tid == 255){ counts[0] = s0[255]; counts[1] = s1[255]; }
}

// ---------------- tiled transpose: src fp32 [2][K][N] -> dst bf16 [2][N][Kpad] ----------------
__global__ __launch_bounds__(256) void transp_kernel(const float* __restrict__ src,
                                                     unsigned short* __restrict__ dst,
                                                     int K, int N, int Kpad, int nkt, int nnt){
    __shared__ float tile[64][65];
    const int tid = threadIdx.x;
    int bid = blockIdx.x;
    const int t  = bid / (nkt*nnt);
    bid -= t*nkt*nnt;
    const int kt = bid / nnt;
    const int nt = bid - kt*nnt;
    const float* s = src + (size_t)t*K*N;
    unsigned short* d = dst + (size_t)t*N*Kpad;

    const int c  = tid & 63;
    const int rg = tid >> 6;
    #pragma unroll
    for (int p = 0; p < 16; ++p){
        int row = p*4 + rg;
        int gr = kt*64 + row, gc = nt*64 + c;
        tile[row][c] = (gr < K && gc < N) ? s[(size_t)gr*N + gc] : 0.0f;
    }
    __syncthreads();
    const int nn0 = tid >> 3;
    const int k8  = (tid & 7) * 8;
    #pragma unroll
    for (int p = 0; p < 2; ++p){
        int nn = p*32 + nn0;
        int gn = nt*64 + nn;
        int gk = kt*64 + k8;
        if (gn < N && gk < Kpad){
            unsigned short v[8];
            #pragma unroll
            for (int j = 0; j < 8; ++j) v[j] = f2bf(tile[k8+j][nn]);
            *(bf16x8*)(d + (size_t)gn*Kpad + gk) = *(bf16x8*)v;
        }
    }
}

// ---------------- small prep: type features + L0 fold Tb + ew1t + ew2t ----------------
__global__ __launch_bounds__(256) void prep_kernel(const float* __restrict__ tv,
                                                   const float* __restrict__ tW0,
                                                   const float* __restrict__ tb0,
                                                   const float* __restrict__ eW0,
                                                   const float* __restrict__ eb0,
                                                   const float* __restrict__ eW1,
                                                   const float* __restrict__ eW2,
                                                   unsigned short* __restrict__ ew1t,
                                                   unsigned short* __restrict__ ew2t,
                                                   float* __restrict__ Tb){
    __shared__ float tfl[16];
    const int tid = threadIdx.x;
    if (tid < 16){
        int t = tid >> 3, f = tid & 7;
        float s = tb0[f];
        #pragma unroll
        for (int p = 0; p < 4; ++p) s = fmaf(tv[t*4+p], tW0[p*8+f], s);
        tfl[tid] = fast_tanh(s) + tv[t*4 + (f & 3)];
    }
    __syncthreads();
    if (tid < 64){
        int t = tid >> 5, o = tid & 31;
        if (o < 25){
            float s = eb0[o];
            #pragma unroll
            for (int k = 0; k < 8; ++k) s = fmaf(tfl[t*8 + k], eW0[(k+1)*25 + o], s);
            Tb[t*32 + o] = s;
        } else {
            Tb[t*32 + o] = 0.0f;
        }
    }
    for (int i = tid; i < 112*64; i += 256){
        int n = i >> 6, k = i & 63;
        ew2t[i] = (n < M1C && k < 50) ? f2bf(eW2[(size_t)k*M1C + n]) : (unsigned short)0;
    }
    for (int i = tid; i < 64*32; i += 256){
        int n = i >> 5, k = i & 31;
        ew1t[i] = (n < 50 && k < 25) ? f2bf(eW1[(size_t)k*50 + n]) : (unsigned short)0;
    }
}

// ---------------- embedding: Ri+L0(folded) fp32, L1+L2 MFMA, de-spilled phase B ----------------
__global__ __launch_bounds__(256, 2) void embed_kernel(
    const float4* __restrict__ imdr,
    const float4* __restrict__ davg,
    const float4* __restrict__ dstd,
    const int*    __restrict__ tmap,
    const float*  __restrict__ eW0,
    const float*  __restrict__ Tb,
    const float*  __restrict__ eb1,
    const float*  __restrict__ eb2,
    const unsigned short* __restrict__ ew1t,
    const unsigned short* __restrict__ ew2t,
    unsigned short* __restrict__ DRout)
{
    __shared__ __align__(16) float Rif[256][4];                 // 4 KB
    __shared__ __align__(16) unsigned short H1s[256][H1STR];    // 20 KB (xyz overlays later)
    __shared__ __align__(16) unsigned short H2s[256][H2STR];    // 36.9 KB

    const int tid = threadIdx.x;
    const int a   = blockIdx.x;
    const int n0  = a & (NATC - 1);
    const int itype = tmap[n0];
    const int j = tid;

    // ---------- phase A: Ri + folded L0 (25 FMA), stage h1 bf16 ----------
    {
        unsigned int* rowp = (unsigned int*)&H1s[j][0];
        if (j < MNTC){
            float4 dr = imdr[(size_t)a*MNTC + j];
            float r  = dr.x;
            float rs = (r > 1e-5f) ? r : 1.0f;
            float ir = __fdividef(1.0f, rs);
            float u  = (r - 0.5f) * (1.0f/5.5f);
            float u2 = u*u, u3 = u2*u;
            float smid = ir * (u3 * (-6.0f*u2 + 15.0f*u - 10.0f) + 1.0f);
            float S = 0.0f;
            if (r > 0.0f && r < 0.5f)       S = ir;
            else if (r >= 0.5f && r < 6.0f) S = smid;
            bool msk = fabsf(r) > 1e-5f;
            float R0 = S;
            float R1 = msk ? S * dr.y * ir : 0.0f;
            float R2 = msk ? S * dr.z * ir : 0.0f;
            float R3 = msk ? S * dr.w * ir : 0.0f;
            float4 av = davg[itype*MNTC + j];
            float4 sv = dstd[itype*MNTC + j];
            float rin0 = __fdividef(R0 - av.x, sv.x);
            float rin1 = __fdividef(R1 - av.y, sv.y);
            float rin2 = __fdividef(R2 - av.z, sv.z);
            float rin3 = __fdividef(R3 - av.w, sv.w);
            Rif[j][0] = rin0; Rif[j][1] = rin1; Rif[j][2] = rin2; Rif[j][3] = rin3;

            const float* tb = Tb + ((j >= 100) ? 32 : 0);
            float h1[25];
            #pragma unroll
            for (int o = 0; o < 25; ++o)
                h1[o] = fast_tanh(fmaf(rin0, eW0[o], tb[o]));

            #pragma unroll
            for (int c = 0; c < 12; ++c) rowp[c] = pack2(h1[2*c], h1[2*c+1]);
            rowp[12] = (unsigned int)f2bf(h1[24]);
            #pragma unroll
            for (int c = 13; c < 20; ++c) rowp[c] = 0u;
        } else {
            Rif[j][0] = 0.0f; Rif[j][1] = 0.0f; Rif[j][2] = 0.0f; Rif[j][3] = 0.0f;
            #pragma unroll
            for (int c = 0; c < 20; ++c) rowp[c] = 0u;
        }
    }
    __syncthreads();

    const int lane = tid & 63;
    const int w    = tid >> 6;
    const int lc   = lane & 15;
    const int lg   = lane >> 4;

    // ---------- L1 via MFMA: M=256, K=32(pad25), N=64(pad50) ----------
    #pragma unroll
    for (int mi = 0; mi < 4; ++mi){
        const int mt = w + mi*4;
        bf16x8 af = *(const bf16x8*)&H1s[mt*16 + lc][lg*8];
        const int rbase = mt*16 + lg*4;
        #pragma unroll
        for (int nt = 0; nt < 4; ++nt){
            const int n = nt*16 + lc;
            const bool live = (n < 50);
            float bv = live ? eb1[n] : 0.0f;
            f32x4 c;
            c[0] = bv; c[1] = bv; c[2] = bv; c[3] = bv;
            bf16x8 bfr = *(const bf16x8*)(ew1t + n*32 + lg*8);
            c = __builtin_amdgcn_mfma_f32_16x16x32_bf16(af, bfr, c, 0, 0, 0);
            const int rc = n % 25;
            #pragma unroll
            for (int i = 0; i < 4; ++i){
                const int row = rbase + i;
                unsigned short v = 0;
                if (live) v = f2bf(fast_tanh(c[i]) + bf2f(H1s[row][rc]));
                H2s[row][n] = v;
            }
        }
    }
    __syncthreads();   // H2s complete; H1s reads done (xyz overlays H1s below)

    // ---------- L2 via MFMA (M=256, K=64, N=112) + xyz reduce, two N-halves ----------
    float* xyzp = (float*)&H1s[0][0];        // [4][4][112] = 7168 B (overlays dead H1s)
    float* xyzs = xyzp + 4*4*112;            // [4][112]    = 1792 B

    #pragma unroll
    for (int half = 0; half < 2; ++half){
        const int ntbase = half * 4;
        float xacc[4][4];
        #pragma unroll
        for (int q = 0; q < 4; ++q)
            #pragma unroll
            for (int d = 0; d < 4; ++d) xacc[q][d] = 0.0f;

        #pragma unroll
        for (int mi = 0; mi < 4; ++mi){
            const int mt = w + mi*4;
            const int rbase = mt*16 + lg*4;
            float4 rj[4];
            #pragma unroll
            for (int i = 0; i < 4; ++i) rj[i] = *(const float4*)&Rif[rbase + i][0];
            const unsigned short* arow = &H2s[mt*16 + lc][0];
            bf16x8 a0 = *(const bf16x8*)(arow + lg*8);
            bf16x8 a1 = *(const bf16x8*)(arow + 32 + lg*8);
            #pragma unroll
            for (int q = 0; q < 4; ++q){
                const int nt = ntbase + q;
                if (nt >= 7) continue;
                const int cg = nt*16 + lc;
                const unsigned short* bp = ew2t + (size_t)cg*64 + lg*8;
                bf16x8 b0 = *(const bf16x8*)(bp);
                bf16x8 b1 = *(const bf16x8*)(bp + 32);
                float bv = (cg < M1C) ? eb2[cg] : 0.0f;
                f32x4 c;
                c[0] = bv; c[1] = bv; c[2] = bv; c[3] = bv;
                c = __builtin_amdgcn_mfma_f32_16x16x32_bf16(a0, b0, c, 0, 0, 0);
                c = __builtin_amdgcn_mfma_f32_16x16x32_bf16(a1, b1, c, 0, 0, 0);
                const int rc = (cg >= 100) ? cg - 100 : ((cg >= 50) ? cg - 50 : cg);
                #pragma unroll
                for (int i = 0; i < 4; ++i){
                    float g = fast_tanh(c[i]) + bf2f(H2s[rbase + i][rc]);
                    xacc[q][0] = fmaf(g, rj[i].x, xacc[q][0]);
                    xacc[q][1] = fmaf(g, rj[i].y, xacc[q][1]);
                    xacc[q][2] = fmaf(g, rj[i].z, xacc[q][2]);
                    xacc[q][3] = fmaf(g, rj[i].w, xacc[q][3]);
                }
            }
        }
        // reduce across lg groups, store partials for this half's columns
        #pragma unroll
        for (int q = 0; q < 4; ++q){
            const int nt = ntbase + q;
            if (nt >= 7) continue;
            #pragma unroll
            for (int d = 0; d < 4; ++d){
                float v = xacc[q][d];
                v += __shfl_xor(v, 16);
                v += __shfl_xor(v, 32);
                if (lane < 16) xyzp[((w*4 + d)*112) + nt*16 + lc] = v;
            }
        }
    }
    __syncthreads();

    // ---------- phase C: combine wave partials ----------
    for (int i = tid; i < 4*112; i += 256){
        int d = i / 112, m = i - d*112;
        xyzs[d*112 + m] = (xyzp[(0*4+d)*112 + m] + xyzp[(1*4+d)*112 + m] +
                           xyzp[(2*4+d)*112 + m] + xyzp[(3*4+d)*112 + m])
                          * (1.0f / (float)MNTC);
    }
    __syncthreads();

    // ---------- phase D: DR = xyz^T @ xyz[:, :16], vectorized bf16x8 store ----------
    if (tid < 200){
        const int i8 = tid * 8;
        const int m  = i8 >> 4;
        const int qb = i8 & 15;          // 0 or 8
        float xm[4], s[8];
        #pragma unroll
        for (int d = 0; d < 4; ++d) xm[d] = xyzs[d*112 + m];
        #pragma unroll
        for (int e = 0; e < 8; ++e){
            float acc = 0.0f;
            #pragma unroll
            for (int d = 0; d < 4; ++d) acc = fmaf(xm[d], xyzs[d*112 + qb + e], acc);
            s[e] = acc;
        }
        unsigned short v[8];
        #pragma unroll
        for (int e = 0; e < 8; ++e) v[e] = f2bf(s[e]);
        *(bf16x8*)(DRout + (size_t)a*(M1C*M2C) + i8) = *(bf16x8*)v;
    }
}

// ---------------- fitting net: bf16 MFMA, 8 atoms/block, 8 waves ----------------
__global__ __launch_bounds__(512) void fitm_kernel(
    const unsigned short* __restrict__ DRbf,   // [4096][1600] bf16
    const int*   __restrict__ idx,
    const int*   __restrict__ counts,
    const unsigned short* __restrict__ w0t,    // [2][240][1600]
    const unsigned short* __restrict__ w1t,    // [2][240][256]
    const unsigned short* __restrict__ w2t,    // [2][240][256]
    const float* __restrict__ fb0,
    const float* __restrict__ fb1,
    const float* __restrict__ fb2,
    const float* __restrict__ fWf,
    const float* __restrict__ fbf,
    float* __restrict__ out)     // out[0..3]=Etot, out[4..]=Ei
{
    const int bid = blockIdx.x;
    const int g = bid & 127;
    const int t = (bid >> 7) & 1;
    const int b = bid >> 8;
    const int cnt  = counts[t];
    const int base = g * 8;
    if (base >= cnt) return;
    const int na = min(8, cnt - base);

    __shared__ int ns[8];
    __shared__ __align__(16) unsigned short hA[16][HSTR];
    __shared__ __align__(16) unsigned short hB[16][HSTR];
    __shared__ float epart[8][16];

    const int tid  = threadIdx.x;
    const int lane = tid & 63;
    const int w    = tid >> 6;       // wave 0..7, owns n-cols [w*32, w*32+32)
    if (tid < 8) ns[tid] = idx[t*NATC + base + ((tid < na) ? tid : 0)];
    __syncthreads();

    const int lc = lane & 15;
    const int lg = lane >> 4;

    int   ncol[2];  bool act[2];  float bias0[2];
    #pragma unroll
    for (int nt = 0; nt < 2; ++nt){
        ncol[nt] = w*32 + nt*16 + lc;
        act[nt]  = (w*32 + nt*16) < FHC;     // wave-uniform
        bias0[nt] = act[nt] ? fb0[t*FHC + ncol[nt]] : 0.0f;
    }

    // A rows 8..15 duplicate rows 0..7 (same atom) -> C rows 8..15 = dup, harmless
    const unsigned short* aptr0 = DRbf + ((size_t)(b*NATC + ns[lc & 7]))*1600 + lg*8;
    const unsigned short* bptr0[2];
    #pragma unroll
    for (int nt = 0; nt < 2; ++nt)
        bptr0[nt] = act[nt] ? (w0t + ((size_t)(t*FHC + ncol[nt]))*1600 + lg*8) : w0t;

    // ---- L0: 1600 -> 240 ----
    f32x4 acc[2];
    #pragma unroll
    for (int nt = 0; nt < 2; ++nt){
        acc[nt][0] = bias0[nt]; acc[nt][1] = bias0[nt];
        acc[nt][2] = bias0[nt]; acc[nt][3] = bias0[nt];
    }
    #pragma unroll 4
    for (int ks = 0; ks < 50; ++ks){
        bf16x8 af = *(const bf16x8*)(aptr0 + ks*32);
        #pragma unroll
        for (int nt = 0; nt < 2; ++nt){
            if (act[nt]){
                bf16x8 bfg = *(const bf16x8*)(bptr0[nt] + ks*32);
                acc[nt] = __builtin_amdgcn_mfma_f32_16x16x32_bf16(af, bfg, acc[nt], 0, 0, 0);
            }
        }
    }
    float h0r[2][4];
    #pragma unroll
    for (int nt = 0; nt < 2; ++nt){
        #pragma unroll
        for (int i = 0; i < 4; ++i){
            int row = lg*4 + i;
            if (act[nt]){
                h0r[nt][i] = fast_tanh(acc[nt][i]);
                hA[row][ncol[nt]] = f2bf(h0r[nt][i]);
            } else {
                h0r[nt][i] = 0.0f;
                hA[row][ncol[nt]] = 0;     // cols 240..255 zero pad
            }
        }
    }
    __syncthreads();

    // ---- L1: 240 -> 240 (+res), K padded to 256 ----
    f32x4 acc1[2];
    #pragma unroll
    for (int nt = 0; nt < 2; ++nt){
        float bv = act[nt] ? fb1[t*FHC + ncol[nt]] : 0.0f;
        acc1[nt][0] = bv; acc1[nt][1] = bv; acc1[nt][2] = bv; acc1[nt][3] = bv;
    }
    const unsigned short* b1p[2];
    #pragma unroll
    for (int nt = 0; nt < 2; ++nt)
        b1p[nt] = act[nt] ? (w1t + ((size_t)(t*FHC + ncol[nt]))*KPAD + lg*8) : w1t;
    #pragma unroll
    for (int ks = 0; ks < 8; ++ks){
        bf16x8 af = *(const bf16x8*)&hA[lc][ks*32 + lg*8];
        #pragma unroll
        for (int nt = 0; nt < 2; ++nt){
            if (act[nt]){
                bf16x8 bfg = *(const bf16x8*)(b1p[nt] + ks*32);
                acc1[nt] = __builtin_amdgcn_mfma_f32_16x16x32_bf16(af, bfg, acc1[nt], 0, 0, 0);
            }
        }
    }
    float h1r[2][4];
    #pragma unroll
    for (int nt = 0; nt < 2; ++nt){
        #pragma unroll
        for (int i = 0; i < 4; ++i){
            int row = lg*4 + i;
            if (act[nt]){
                h1r[nt][i] = fast_tanh(acc1[nt][i]) + h0r[nt][i];
                hB[row][ncol[nt]] = f2bf(h1r[nt][i]);
            } else {
                h1r[nt][i] = 0.0f;
                hB[row][ncol[nt]] = 0;
            }
        }
    }
    __syncthreads();

    // ---- L2: 240 -> 240 (+res) ----
    f32x4 acc2[2];
    #pragma unroll
    for (int nt = 0; nt < 2; ++nt){
        float bv = act[nt] ? fb2[t*FHC + ncol[nt]] : 0.0f;
        acc2[nt][0] = bv; acc2[nt][1] = bv; acc2[nt][2] = bv; acc2[nt][3] = bv;
    }
    const unsigned short* b2p[2];
    #pragma unroll
    for (int nt = 0; nt < 2; ++nt)
        b2p[nt] = act[nt] ? (w2t + ((size_t)(t*FHC + ncol[nt]))*KPAD + lg*8) : w2t;
    #pragma unroll
    for (int ks = 0; ks < 8; ++ks){
        bf16x8 af = *(const bf16x8*)&hB[lc][ks*32 + lg*8];
        #pragma unroll
        for (int nt = 0; nt < 2; ++nt){
            if (act[nt]){
                bf16x8 bfg = *(const bf16x8*)(b2p[nt] + ks*32);
                acc2[nt] = __builtin_amdgcn_mfma_f32_16x16x32_bf16(af, bfg, acc2[nt], 0, 0, 0);
            }
        }
    }

    // ---- final: e = sum_n h2*wf + fbf ----
    float p0 = 0.0f, p1 = 0.0f, p2 = 0.0f, p3 = 0.0f;
    #pragma unroll
    for (int nt = 0; nt < 2; ++nt){
        if (act[nt]){
            float wfv = fWf[t*FHC + ncol[nt]];
            float h;
            h = fast_tanh(acc2[nt][0]) + h1r[nt][0]; p0 = fmaf(h, wfv, p0);
            h = fast_tanh(acc2[nt][1]) + h1r[nt][1]; p1 = fmaf(h, wfv, p1);
            h = fast_tanh(acc2[nt][2]) + h1r[nt][2]; p2 = fmaf(h, wfv, p2);
            h = fast_tanh(acc2[nt][3]) + h1r[nt][3]; p3 = fmaf(h, wfv, p3);
        }
    }
    #pragma unroll
    for (int off = 1; off < 16; off <<= 1){
        p0 += __shfl_xor(p0, off);
        p1 += __shfl_xor(p1, off);
        p2 += __shfl_xor(p2, off);
        p3 += __shfl_xor(p3, off);
    }
    if (lc == 0){
        epart[w][lg*4 + 0] = p0;
        epart[w][lg*4 + 1] = p1;
        epart[w][lg*4 + 2] = p2;
        epart[w][lg*4 + 3] = p3;
    }
    __syncthreads();
    if (tid < 8){
        float e = fbf[t];
        #pragma unroll
        for (int ww = 0; ww < 8; ++ww) e += epart[ww][tid];
        float ee = 0.0f;
        if (tid < na){
            out[4 + b*NATC + ns[tid]] = e;
            ee = e;
        }
        #pragma unroll
        for (int off = 4; off >= 1; off >>= 1) ee += __shfl_down(ee, off, 8);
        if (tid == 0) atomicAdd(&out[b], ee);
    }
}

extern "C" void kernel_launch(void* const* d_in, const int* in_sizes, int n_in,
                              void* d_out, int out_size, void* d_ws, size_t ws_size,
                              hipStream_t stream)
{
    (void)in_sizes; (void)n_in; (void)out_size; (void)ws_size;
    const int*   tmap = (const int*)d_in[1];
    const float* imdr = (const float*)d_in[3];
    const float* davg = (const float*)d_in[5];
    const float* dstd = (const float*)d_in[6];
    const float* tv   = (const float*)d_in[7];
    const float* tW0  = (const float*)d_in[8];
    const float* tb0  = (const float*)d_in[9];
    const float* eW0  = (const float*)d_in[10];
    const float* eb0  = (const float*)d_in[11];
    const float* eW1  = (const float*)d_in[12];
    const float* eb1  = (const float*)d_in[13];
    const float* eW2  = (const float*)d_in[14];
    const float* eb2  = (const float*)d_in[15];
    const float* fW0  = (const float*)d_in[16];
    const float* fb0  = (const float*)d_in[17];
    const float* fW1  = (const float*)d_in[18];
    const float* fb1  = (const float*)d_in[19];
    const float* fW2  = (const float*)d_in[20];
    const float* fb2  = (const float*)d_in[21];
    const float* fWf  = (const float*)d_in[22];
    const float* fbf  = (const float*)d_in[23];
    float* out = (float*)d_out;

    char* ws = (char*)d_ws;
    int*   counts = (int*)ws;
    int*   idx    = (int*)(ws + 64);
    unsigned short* DRbf = (unsigned short*)(ws + 16384);
    unsigned short* w0t  = DRbf + (size_t)BATCH*NATC*1600;        // 13,107,200 B
    unsigned short* w1t  = w0t + (size_t)2*FHC*1600;              // 1,536,000 B
    unsigned short* w2t  = w1t + (size_t)2*FHC*KPAD;              // 245,760 B
    unsigned short* ew2t = w2t + (size_t)2*FHC*KPAD;              // 245,760 B
    unsigned short* ew1t = ew2t + 112*64;                         // 14,336 B
    float* Tb            = (float*)(ew1t + 64*32);                // 4,096 B -> 256 B used

    hipMemsetAsync(d_out, 0, 4*sizeof(float), stream);
    part_kernel<<<1, 256, 0, stream>>>(tmap, idx, counts);
    prep_kernel<<<1, 256, 0, stream>>>(tv, tW0, tb0, eW0, eb0, eW1, eW2, ew1t, ew2t, Tb);
    transp_kernel<<<2*25*4, 256, 0, stream>>>(fW0, w0t, 1600, FHC, 1600, 25, 4);
    transp_kernel<<<2*4*4,  256, 0, stream>>>(fW1, w1t, FHC, FHC, KPAD, 4, 4);
    transp_kernel<<<2*4*4,  256, 0, stream>>>(fW2, w2t, FHC, FHC, KPAD, 4, 4);
    embed_kernel<<<BATCH*NATC, 256, 0, stream>>>(
        (const float4*)imdr, (const float4*)davg, (const float4*)dstd, tmap,
        eW0, Tb, eb1, eb2, ew1t, ew2t, DRbf);
    fitm_kernel<<<1024, 512, 0, stream>>>(
        DRbf, idx, counts, w0t, w1t, w2t, fb0, fb1, fb2, fWf, fbf, out);
}

// Round 7
// 373.164 us; speedup vs baseline: 1.3020x; 1.3020x over previous
//
#include <hip/hip_runtime.h>
#include <hip/hip_bf16.h>

#define NATC  1024
#define BATCH 4
#define MNTC  200
#define M1C   100
#define M2C   16
#define FHC   240
#define KPAD  256
#define HSTR  264   // fitm LDS h row stride (bf16): 528B rows, 16B-aligned
#define H1STR 40    // embed h1 stage stride (bf16): 80B rows
#define H2STR 72    // embed h2 stage stride (bf16): 144B rows
#define NR    128   // neighbor rows per embed block (half of 256)

typedef __attribute__((ext_vector_type(8))) short bf16x8;
typedef __attribute__((ext_vector_type(4))) float f32x4;

__device__ __forceinline__ float fast_tanh(float x){
    float e = __expf(2.0f * x);
    float r = __fdividef(1.0f, e + 1.0f);
    return fmaf(-2.0f, r, 1.0f);
}

__device__ __forceinline__ unsigned short f2bf(float x){
    __hip_bfloat16 h = __float2bfloat16(x);
    return *reinterpret_cast<unsigned short*>(&h);
}

__device__ __forceinline__ float bf2f(unsigned short u){
    unsigned int v = ((unsigned int)u) << 16;
    return *reinterpret_cast<float*>(&v);
}

__device__ __forceinline__ unsigned int pack2(float a, float b){
    return (unsigned int)f2bf(a) | ((unsigned int)f2bf(b) << 16);
}

// ---------------- partition atoms by type (deterministic) ----------------
__global__ __launch_bounds__(256) void part_kernel(const int* __restrict__ tmap,
                                                   int* __restrict__ idx,
                                                   int* __restrict__ counts){
    __shared__ int s0[256], s1[256];
    const int tid = threadIdx.x;
    int ty[4]; int c0 = 0, c1 = 0;
    #pragma unroll
    for (int r = 0; r < 4; ++r){
        ty[r] = tmap[tid*4 + r];
        if (ty[r] == 0) c0++; else c1++;
    }
    s0[tid] = c0; s1[tid] = c1;
    __syncthreads();
    for (int off = 1; off < 256; off <<= 1){
        int v0 = (tid >= off) ? s0[tid-off] : 0;
        int v1 = (tid >= off) ? s1[tid-off] : 0;
        __syncthreads();
        s0[tid] += v0; s1[tid] += v1;
        __syncthreads();
    }
    int e0 = s0[tid] - c0, e1 = s1[tid] - c1;
    #pragma unroll
    for (int r = 0; r < 4; ++r){
        int n = tid*4 + r;
        if (ty[r] == 0) idx[e0++] = n; else idx[NATC + e1++] = n;
    }
    if (tid == 255){ counts[0] = s0[255]; counts[1] = s1[255]; }
}

// ---------------- tiled transpose: src fp32 [2][K][N] -> dst bf16 [2][N][Kpad] ----------------
__global__ __launch_bounds__(256) void transp_kernel(const float* __restrict__ src,
                                                     unsigned short* __restrict__ dst,
                                                     int K, int N, int Kpad, int nkt, int nnt){
    __shared__ float tile[64][65];
    const int tid = threadIdx.x;
    int bid = blockIdx.x;
    const int t  = bid / (nkt*nnt);
    bid -= t*nkt*nnt;
    const int kt = bid / nnt;
    const int nt = bid - kt*nnt;
    const float* s = src + (size_t)t*K*N;
    unsigned short* d = dst + (size_t)t*N*Kpad;

    const int c  = tid & 63;
    const int rg = tid >> 6;
    #pragma unroll
    for (int p = 0; p < 16; ++p){
        int row = p*4 + rg;
        int gr = kt*64 + row, gc = nt*64 + c;
        tile[row][c] = (gr < K && gc < N) ? s[(size_t)gr*N + gc] : 0.0f;
    }
    __syncthreads();
    const int nn0 = tid >> 3;
    const int k8  = (tid & 7) * 8;
    #pragma unroll
    for (int p = 0; p < 2; ++p){
        int nn = p*32 + nn0;
        int gn = nt*64 + nn;
        int gk = kt*64 + k8;
        if (gn < N && gk < Kpad){
            unsigned short v[8];
            #pragma unroll
            for (int j = 0; j < 8; ++j) v[j] = f2bf(tile[k8+j][nn]);
            *(bf16x8*)(d + (size_t)gn*Kpad + gk) = *(bf16x8*)v;
        }
    }
}

// ---------------- small prep: type features + L0 fold Tb + ew1t + ew2t ----------------
__global__ __launch_bounds__(256) void prep_kernel(const float* __restrict__ tv,
                                                   const float* __restrict__ tW0,
                                                   const float* __restrict__ tb0,
                                                   const float* __restrict__ eW0,
                                                   const float* __restrict__ eb0,
                                                   const float* __restrict__ eW1,
                                                   const float* __restrict__ eW2,
                                                   unsigned short* __restrict__ ew1t,
                                                   unsigned short* __restrict__ ew2t,
                                                   float* __restrict__ Tb){
    __shared__ float tfl[16];
    const int tid = threadIdx.x;
    if (tid < 16){
        int t = tid >> 3, f = tid & 7;
        float s = tb0[f];
        #pragma unroll
        for (int p = 0; p < 4; ++p) s = fmaf(tv[t*4+p], tW0[p*8+f], s);
        tfl[tid] = fast_tanh(s) + tv[t*4 + (f & 3)];
    }
    __syncthreads();
    if (tid < 64){
        int t = tid >> 5, o = tid & 31;
        if (o < 25){
            float s = eb0[o];
            #pragma unroll
            for (int k = 0; k < 8; ++k) s = fmaf(tfl[t*8 + k], eW0[(k+1)*25 + o], s);
            Tb[t*32 + o] = s;
        } else {
            Tb[t*32 + o] = 0.0f;
        }
    }
    for (int i = tid; i < 112*64; i += 256){
        int n = i >> 6, k = i & 63;
        ew2t[i] = (n < M1C && k < 50) ? f2bf(eW2[(size_t)k*M1C + n]) : (unsigned short)0;
    }
    for (int i = tid; i < 64*32; i += 256){
        int n = i >> 5, k = i & 31;
        ew1t[i] = (n < 50 && k < 25) ? f2bf(eW1[(size_t)k*50 + n]) : (unsigned short)0;
    }
}

// ---- embedding (split): each block = (atom a, neighbor-half jh), 128 rows ----
__global__ __launch_bounds__(256, 4) void embed_kernel(
    const float4* __restrict__ imdr,
    const float4* __restrict__ davg,
    const float4* __restrict__ dstd,
    const int*    __restrict__ tmap,
    const float*  __restrict__ eW0,
    const float*  __restrict__ Tb,
    const float*  __restrict__ eb1,
    const float*  __restrict__ eb2,
    const unsigned short* __restrict__ ew1t,
    const unsigned short* __restrict__ ew2t,
    float* __restrict__ xyzg)        // [4096][2][448]
{
    __shared__ __align__(16) float Rif[NR][4];                 // 2 KB
    __shared__ __align__(16) unsigned short H1s[NR][H1STR];    // 10 KB (xyzp overlays later)
    __shared__ __align__(16) unsigned short H2s[NR][H2STR];    // 18.4 KB

    const int tid = threadIdx.x;
    const int bid = blockIdx.x;
    const int a   = bid >> 1;
    const int jh  = bid & 1;
    const int n0  = a & (NATC - 1);
    const int itype = tmap[n0];

    // ---------- phase A: Ri + folded L0 (25 FMA), stage h1 bf16 ----------
    if (tid < NR){
        const int jg = jh*NR + tid;
        unsigned int* rowp = (unsigned int*)&H1s[tid][0];
        if (jg < MNTC){
            float4 dr = imdr[(size_t)a*MNTC + jg];
            float r  = dr.x;
            float rs = (r > 1e-5f) ? r : 1.0f;
            float ir = __fdividef(1.0f, rs);
            float u  = (r - 0.5f) * (1.0f/5.5f);
            float u2 = u*u, u3 = u2*u;
            float smid = ir * (u3 * (-6.0f*u2 + 15.0f*u - 10.0f) + 1.0f);
            float S = 0.0f;
            if (r > 0.0f && r < 0.5f)       S = ir;
            else if (r >= 0.5f && r < 6.0f) S = smid;
            bool msk = fabsf(r) > 1e-5f;
            float R0 = S;
            float R1 = msk ? S * dr.y * ir : 0.0f;
            float R2 = msk ? S * dr.z * ir : 0.0f;
            float R3 = msk ? S * dr.w * ir : 0.0f;
            float4 av = davg[itype*MNTC + jg];
            float4 sv = dstd[itype*MNTC + jg];
            float rin0 = __fdividef(R0 - av.x, sv.x);
            float rin1 = __fdividef(R1 - av.y, sv.y);
            float rin2 = __fdividef(R2 - av.z, sv.z);
            float rin3 = __fdividef(R3 - av.w, sv.w);
            Rif[tid][0] = rin0; Rif[tid][1] = rin1; Rif[tid][2] = rin2; Rif[tid][3] = rin3;

            const float* tb = Tb + ((jg >= 100) ? 32 : 0);
            float h1[25];
            #pragma unroll
            for (int o = 0; o < 25; ++o)
                h1[o] = fast_tanh(fmaf(rin0, eW0[o], tb[o]));

            #pragma unroll
            for (int c = 0; c < 12; ++c) rowp[c] = pack2(h1[2*c], h1[2*c+1]);
            rowp[12] = (unsigned int)f2bf(h1[24]);
            #pragma unroll
            for (int c = 13; c < 20; ++c) rowp[c] = 0u;
        } else {
            Rif[tid][0] = 0.0f; Rif[tid][1] = 0.0f; Rif[tid][2] = 0.0f; Rif[tid][3] = 0.0f;
            #pragma unroll
            for (int c = 0; c < 20; ++c) rowp[c] = 0u;
        }
    }
    __syncthreads();

    const int lane = tid & 63;
    const int w    = tid >> 6;
    const int lc   = lane & 15;
    const int lg   = lane >> 4;

    // ---------- L1 via MFMA: M=128, K=32(pad25), N=64(pad50) ----------
    #pragma unroll
    for (int mi = 0; mi < 2; ++mi){
        const int mt = w + mi*4;                 // 0..7
        bf16x8 af = *(const bf16x8*)&H1s[mt*16 + lc][lg*8];
        const int rbase = mt*16 + lg*4;
        #pragma unroll
        for (int nt = 0; nt < 4; ++nt){
            const int n = nt*16 + lc;
            const bool live = (n < 50);
            float bv = live ? eb1[n] : 0.0f;
            f32x4 c;
            c[0] = bv; c[1] = bv; c[2] = bv; c[3] = bv;
            bf16x8 bfr = *(const bf16x8*)(ew1t + n*32 + lg*8);
            c = __builtin_amdgcn_mfma_f32_16x16x32_bf16(af, bfr, c, 0, 0, 0);
            const int rc = n % 25;
            #pragma unroll
            for (int i = 0; i < 4; ++i){
                const int row = rbase + i;
                unsigned short v = 0;
                if (live) v = f2bf(fast_tanh(c[i]) + bf2f(H1s[row][rc]));
                H2s[row][n] = v;
            }
        }
    }
    __syncthreads();   // H2s complete; H1s reads done (xyzp overlays H1s below)

    // ---------- L2 via MFMA (M=128, K=64, N=112) + xyz reduce, two N-halves ----------
    float* xyzp = (float*)&H1s[0][0];        // [4 waves][4][112] = 7168 B overlay

    #pragma unroll
    for (int half = 0; half < 2; ++half){
        const int ntbase = half * 4;
        float xacc[4][4];
        #pragma unroll
        for (int q = 0; q < 4; ++q)
            #pragma unroll
            for (int d = 0; d < 4; ++d) xacc[q][d] = 0.0f;

        #pragma unroll
        for (int mi = 0; mi < 2; ++mi){
            const int mt = w + mi*4;
            const int rbase = mt*16 + lg*4;
            float4 rj[4];
            #pragma unroll
            for (int i = 0; i < 4; ++i) rj[i] = *(const float4*)&Rif[rbase + i][0];
            const unsigned short* arow = &H2s[mt*16 + lc][0];
            bf16x8 a0 = *(const bf16x8*)(arow + lg*8);
            bf16x8 a1 = *(const bf16x8*)(arow + 32 + lg*8);
            #pragma unroll
            for (int q = 0; q < 4; ++q){
                const int nt = ntbase + q;
                if (nt >= 7) continue;
                const int cg = nt*16 + lc;
                const unsigned short* bp = ew2t + (size_t)cg*64 + lg*8;
                bf16x8 b0 = *(const bf16x8*)(bp);
                bf16x8 b1 = *(const bf16x8*)(bp + 32);
                float bv = (cg < M1C) ? eb2[cg] : 0.0f;
                f32x4 c;
                c[0] = bv; c[1] = bv; c[2] = bv; c[3] = bv;
                c = __builtin_amdgcn_mfma_f32_16x16x32_bf16(a0, b0, c, 0, 0, 0);
                c = __builtin_amdgcn_mfma_f32_16x16x32_bf16(a1, b1, c, 0, 0, 0);
                const int rc = (cg >= 100) ? cg - 100 : ((cg >= 50) ? cg - 50 : cg);
                #pragma unroll
                for (int i = 0; i < 4; ++i){
                    float g = fast_tanh(c[i]) + bf2f(H2s[rbase + i][rc]);
                    xacc[q][0] = fmaf(g, rj[i].x, xacc[q][0]);
                    xacc[q][1] = fmaf(g, rj[i].y, xacc[q][1]);
                    xacc[q][2] = fmaf(g, rj[i].z, xacc[q][2]);
                    xacc[q][3] = fmaf(g, rj[i].w, xacc[q][3]);
                }
            }
        }
        #pragma unroll
        for (int q = 0; q < 4; ++q){
            const int nt = ntbase + q;
            if (nt >= 7) continue;
            #pragma unroll
            for (int d = 0; d < 4; ++d){
                float v = xacc[q][d];
                v += __shfl_xor(v, 16);
                v += __shfl_xor(v, 32);
                if (lane < 16) xyzp[((w*4 + d)*112) + nt*16 + lc] = v;
            }
        }
    }
    __syncthreads();

    // ---------- combine 4 wave partials -> global xyzg[a][jh][448] ----------
    for (int i = tid; i < 448; i += 256){
        int d = i / 112, m = i - d*112;
        xyzg[(size_t)a*896 + jh*448 + i] =
            xyzp[(0*4+d)*112 + m] + xyzp[(1*4+d)*112 + m] +
            xyzp[(2*4+d)*112 + m] + xyzp[(3*4+d)*112 + m];
    }
}

// ---------------- DR: combine halves, DR = xyz^T @ xyz[:, :16] -> bf16 ----------------
__global__ __launch_bounds__(256) void dr_kernel(const float* __restrict__ xyzg,
                                                 unsigned short* __restrict__ DRout){
    __shared__ float xyzs[448];
    const int a = blockIdx.x;
    const int tid = threadIdx.x;
    for (int i = tid; i < 448; i += 256)
        xyzs[i] = (xyzg[(size_t)a*896 + i] + xyzg[(size_t)a*896 + 448 + i]) * (1.0f / (float)MNTC);
    __syncthreads();
    if (tid < 200){
        const int i8 = tid * 8;
        const int m  = i8 >> 4;
        const int qb = i8 & 15;
        float xm[4], s[8];
        #pragma unroll
        for (int d = 0; d < 4; ++d) xm[d] = xyzs[d*112 + m];
        #pragma unroll
        for (int e = 0; e < 8; ++e){
            float acc = 0.0f;
            #pragma unroll
            for (int d = 0; d < 4; ++d) acc = fmaf(xm[d], xyzs[d*112 + qb + e], acc);
            s[e] = acc;
        }
        unsigned short v[8];
        #pragma unroll
        for (int e = 0; e < 8; ++e) v[e] = f2bf(s[e]);
        *(bf16x8*)(DRout + (size_t)a*(M1C*M2C) + i8) = *(bf16x8*)v;
    }
}

// ------- fitting net: bf16 MFMA, 32 atoms/block, 8 waves, type->XCD affinity -------
__global__ __launch_bounds__(512, 2) void fitm_kernel(
    const unsigned short* __restrict__ DRbf,   // [4096][1600] bf16
    const int*   __restrict__ idx,
    const int*   __restrict__ counts,
    const unsigned short* __restrict__ w0t,    // [2][240][1600]
    const unsigned short* __restrict__ w1t,    // [2][240][256]
    const unsigned short* __restrict__ w2t,    // [2][240][256]
    const float* __restrict__ fb0,
    const float* __restrict__ fb1,
    const float* __restrict__ fb2,
    const float* __restrict__ fWf,
    const float* __restrict__ fbf,
    float* __restrict__ out)     // out[0..3]=Etot, out[4..]=Ei
{
    const int bid = blockIdx.x;
    const int t = bid & 1;               // low bit -> XCD parity: type weights stay in one XCD's L2
    const int g = (bid >> 1) & 31;
    const int b = bid >> 6;
    const int cnt  = counts[t];
    const int base = g * 32;
    if (base >= cnt) return;
    const int na = min(32, cnt - base);

    __shared__ int ns[32];
    __shared__ __align__(16) unsigned short hA[32][HSTR];
    __shared__ __align__(16) unsigned short hB[32][HSTR];
    __shared__ float epart[8][32];

    const int tid  = threadIdx.x;
    const int lane = tid & 63;
    const int w    = tid >> 6;       // wave 0..7, owns n-cols [w*32, w*32+32)
    if (tid < 32) ns[tid] = idx[t*NATC + base + ((tid < na) ? tid : 0)];
    __syncthreads();

    const int lc = lane & 15;
    const int lg = lane >> 4;

    int   ncol[2];  bool act[2];
    #pragma unroll
    for (int nt = 0; nt < 2; ++nt){
        ncol[nt] = w*32 + nt*16 + lc;
        act[nt]  = (w*32 + nt*16) < FHC;     // wave-uniform
    }

    const unsigned short* aptr[2];
    aptr[0] = DRbf + ((size_t)(b*NATC + ns[lc]))*1600 + lg*8;
    aptr[1] = DRbf + ((size_t)(b*NATC + ns[16 + lc]))*1600 + lg*8;
    const unsigned short* bptr0[2];
    #pragma unroll
    for (int nt = 0; nt < 2; ++nt)
        bptr0[nt] = act[nt] ? (w0t + ((size_t)(t*FHC + ncol[nt]))*1600 + lg*8) : w0t;

    // ---- L0: 1600 -> 240, 2 M-tiles x 2 N-tiles ----
    f32x4 acc[2][2];
    #pragma unroll
    for (int mi = 0; mi < 2; ++mi)
        #pragma unroll
        for (int nt = 0; nt < 2; ++nt){
            float bv = act[nt] ? fb0[t*FHC + ncol[nt]] : 0.0f;
            acc[mi][nt][0] = bv; acc[mi][nt][1] = bv; acc[mi][nt][2] = bv; acc[mi][nt][3] = bv;
        }
    #pragma unroll 4
    for (int ks = 0; ks < 50; ++ks){
        bf16x8 a0 = *(const bf16x8*)(aptr[0] + ks*32);
        bf16x8 a1 = *(const bf16x8*)(aptr[1] + ks*32);
        #pragma unroll
        for (int nt = 0; nt < 2; ++nt){
            if (act[nt]){
                bf16x8 bfg = *(const bf16x8*)(bptr0[nt] + ks*32);
                acc[0][nt] = __builtin_amdgcn_mfma_f32_16x16x32_bf16(a0, bfg, acc[0][nt], 0, 0, 0);
                acc[1][nt] = __builtin_amdgcn_mfma_f32_16x16x32_bf16(a1, bfg, acc[1][nt], 0, 0, 0);
            }
        }
    }
    float h0r[2][2][4];
    #pragma unroll
    for (int mi = 0; mi < 2; ++mi)
        #pragma unroll
        for (int nt = 0; nt < 2; ++nt)
            #pragma unroll
            for (int i = 0; i < 4; ++i){
                int row = mi*16 + lg*4 + i;
                if (act[nt]){
                    h0r[mi][nt][i] = fast_tanh(acc[mi][nt][i]);
                    hA[row][ncol[nt]] = f2bf(h0r[mi][nt][i]);
                } else {
                    h0r[mi][nt][i] = 0.0f;
                    hA[row][ncol[nt]] = 0;     // cols 240..255 zero pad
                }
            }
    __syncthreads();

    // ---- L1: 240 -> 240 (+res), K padded to 256 ----
    f32x4 acc1[2][2];
    #pragma unroll
    for (int mi = 0; mi < 2; ++mi)
        #pragma unroll
        for (int nt = 0; nt < 2; ++nt){
            float bv = act[nt] ? fb1[t*FHC + ncol[nt]] : 0.0f;
            acc1[mi][nt][0] = bv; acc1[mi][nt][1] = bv; acc1[mi][nt][2] = bv; acc1[mi][nt][3] = bv;
        }
    const unsigned short* b1p[2];
    #pragma unroll
    for (int nt = 0; nt < 2; ++nt)
        b1p[nt] = act[nt] ? (w1t + ((size_t)(t*FHC + ncol[nt]))*KPAD + lg*8) : w1t;
    #pragma unroll
    for (int ks = 0; ks < 8; ++ks){
        bf16x8 a0 = *(const bf16x8*)&hA[lc][ks*32 + lg*8];
        bf16x8 a1 = *(const bf16x8*)&hA[16 + lc][ks*32 + lg*8];
        #pragma unroll
        for (int nt = 0; nt < 2; ++nt){
            if (act[nt]){
                bf16x8 bfg = *(const bf16x8*)(b1p[nt] + ks*32);
                acc1[0][nt] = __builtin_amdgcn_mfma_f32_16x16x32_bf16(a0, bfg, acc1[0][nt], 0, 0, 0);
                acc1[1][nt] = __builtin_amdgcn_mfma_f32_16x16x32_bf16(a1, bfg, acc1[1][nt], 0, 0, 0);
            }
        }
    }
    float h1r[2][2][4];
    #pragma unroll
    for (int mi = 0; mi < 2; ++mi)
        #pragma unroll
        for (int nt = 0; nt < 2; ++nt)
            #pragma unroll
            for (int i = 0; i < 4; ++i){
                int row = mi*16 + lg*4 + i;
                if (act[nt]){
                    h1r[mi][nt][i] = fast_tanh(acc1[mi][nt][i]) + h0r[mi][nt][i];
                    hB[row][ncol[nt]] = f2bf(h1r[mi][nt][i]);
                } else {
                    h1r[mi][nt][i] = 0.0f;
                    hB[row][ncol[nt]] = 0;
                }
            }
    __syncthreads();

    // ---- L2: 240 -> 240 (+res) ----
    f32x4 acc2[2][2];
    #pragma unroll
    for (int mi = 0; mi < 2; ++mi)
        #pragma unroll
        for (int nt = 0; nt < 2; ++nt){
            float bv = act[nt] ? fb2[t*FHC + ncol[nt]] : 0.0f;
            acc2[mi][nt][0] = bv; acc2[mi][nt][1] = bv; acc2[mi][nt][2] = bv; acc2[mi][nt][3] = bv;
        }
    const unsigned short* b2p[2];
    #pragma unroll
    for (int nt = 0; nt < 2; ++nt)
        b2p[nt] = act[nt] ? (w2t + ((size_t)(t*FHC + ncol[nt]))*KPAD + lg*8) : w2t;
    #pragma unroll
    for (int ks = 0; ks < 8; ++ks){
        bf16x8 a0 = *(const bf16x8*)&hB[lc][ks*32 + lg*8];
        bf16x8 a1 = *(const bf16x8*)&hB[16 + lc][ks*32 + lg*8];
        #pragma unroll
        for (int nt = 0; nt < 2; ++nt){
            if (act[nt]){
                bf16x8 bfg = *(const bf16x8*)(b2p[nt] + ks*32);
                acc2[0][nt] = __builtin_amdgcn_mfma_f32_16x16x32_bf16(a0, bfg, acc2[0][nt], 0, 0, 0);
                acc2[1][nt] = __builtin_amdgcn_mfma_f32_16x16x32_bf16(a1, bfg, acc2[1][nt], 0, 0, 0);
            }
        }
    }

    // ---- final: e = sum_n h2*wf + fbf ----
    float p[2][4];
    #pragma unroll
    for (int mi = 0; mi < 2; ++mi)
        #pragma unroll
        for (int i = 0; i < 4; ++i) p[mi][i] = 0.0f;
    #pragma unroll
    for (int nt = 0; nt < 2; ++nt){
        if (act[nt]){
            float wfv = fWf[t*FHC + ncol[nt]];
            #pragma unroll
            for (int mi = 0; mi < 2; ++mi)
                #pragma unroll
                for (int i = 0; i < 4; ++i){
                    float h = fast_tanh(acc2[mi][nt][i]) + h1r[mi][nt][i];
                    p[mi][i] = fmaf(h, wfv, p[mi][i]);
                }
        }
    }
    #pragma unroll
    for (int off = 1; off < 16; off <<= 1){
        #pragma unroll
        for (int mi = 0; mi < 2; ++mi)
            #pragma unroll
            for (int i = 0; i < 4; ++i)
                p[mi][i] += __shfl_xor(p[mi][i], off);
    }
    if (lc == 0){
        #pragma unroll
        for (int mi = 0; mi < 2; ++mi)
            #pragma unroll
            for (int i = 0; i < 4; ++i)
                epart[w][mi*16 + lg*4 + i] = p[mi][i];
    }
    __syncthreads();
    if (tid < 32){
        float e = fbf[t];
        #pragma unroll
        for (int ww = 0; ww < 8; ++ww) e += epart[ww][tid];
        float ee = 0.0f;
        if (tid < na){
            out[4 + b*NATC + ns[tid]] = e;
            ee = e;
        }
        #pragma unroll
        for (int off = 16; off >= 1; off >>= 1) ee += __shfl_down(ee, off, 32);
        if (tid == 0) atomicAdd(&out[b], ee);
    }
}

extern "C" void kernel_launch(void* const* d_in, const int* in_sizes, int n_in,
                              void* d_out, int out_size, void* d_ws, size_t ws_size,
                              hipStream_t stream)
{
    (void)in_sizes; (void)n_in; (void)out_size; (void)ws_size;
    const int*   tmap = (const int*)d_in[1];
    const float* imdr = (const float*)d_in[3];
    const float* davg = (const float*)d_in[5];
    const float* dstd = (const float*)d_in[6];
    const float* tv   = (const float*)d_in[7];
    const float* tW0  = (const float*)d_in[8];
    const float* tb0  = (const float*)d_in[9];
    const float* eW0  = (const float*)d_in[10];
    const float* eb0  = (const float*)d_in[11];
    const float* eW1  = (const float*)d_in[12];
    const float* eb1  = (const float*)d_in[13];
    const float* eW2  = (const float*)d_in[14];
    const float* eb2  = (const float*)d_in[15];
    const float* fW0  = (const float*)d_in[16];
    const float* fb0  = (const float*)d_in[17];
    const float* fW1  = (const float*)d_in[18];
    const float* fb1  = (const float*)d_in[19];
    const float* fW2  = (const float*)d_in[20];
    const float* fb2  = (const float*)d_in[21];
    const float* fWf  = (const float*)d_in[22];
    const float* fbf  = (const float*)d_in[23];
    float* out = (float*)d_out;

    char* ws = (char*)d_ws;
    int*   counts = (int*)ws;
    int*   idx    = (int*)(ws + 64);
    unsigned short* DRbf = (unsigned short*)(ws + 16384);
    unsigned short* w0t  = DRbf + (size_t)BATCH*NATC*1600;        // 13,107,200 B
    unsigned short* w1t  = w0t + (size_t)2*FHC*1600;              // 1,536,000 B
    unsigned short* w2t  = w1t + (size_t)2*FHC*KPAD;              // 245,760 B
    unsigned short* ew2t = w2t + (size_t)2*FHC*KPAD;              // 245,760 B
    unsigned short* ew1t = ew2t + 112*64;                         // 14,336 B
    float* Tb            = (float*)(ew1t + 64*32);                // 256 B used
    float* xyzg          = (float*)((char*)Tb + 4096);            // 4096*896*4 = 14.68 MB

    hipMemsetAsync(d_out, 0, 4*sizeof(float), stream);
    part_kernel<<<1, 256, 0, stream>>>(tmap, idx, counts);
    prep_kernel<<<1, 256, 0, stream>>>(tv, tW0, tb0, eW0, eb0, eW1, eW2, ew1t, ew2t, Tb);
    transp_kernel<<<2*25*4, 256, 0, stream>>>(fW0, w0t, 1600, FHC, 1600, 25, 4);
    transp_kernel<<<2*4*4,  256, 0, stream>>>(fW1, w1t, FHC, FHC, KPAD, 4, 4);
    transp_kernel<<<2*4*4,  256, 0, stream>>>(fW2, w2t, FHC, FHC, KPAD, 4, 4);
    embed_kernel<<<2*BATCH*NATC, 256, 0, stream>>>(
        (const float4*)imdr, (const float4*)davg, (const float4*)dstd, tmap,
        eW0, Tb, eb1, eb2, ew1t, ew2t, xyzg);
    dr_kernel<<<BATCH*NATC, 256, 0, stream>>>(xyzg, DRbf);
    fitm_kernel<<<256, 512, 0, stream>>>(
        DRbf, idx, counts, w0t, w1t, w2t, fb0, fb1, fb2, fWf, fbf, out);
}

// Round 8
// 357.051 us; speedup vs baseline: 1.3608x; 1.0451x over previous
//
#include <hip/hip_runtime.h>
#include <hip/hip_bf16.h>

#define NATC  1024
#define BATCH 4
#define MNTC  200
#define M1C   100
#define M2C   16
#define FHC   240
#define NPAD  256   // fitting N padded (cols 240..255 zero)
#define H1STR 40    // embed h1 stage stride (bf16): 80B rows
#define H2STR 72    // embed h2 stage stride (bf16): 144B rows
#define NR    128   // neighbor rows per embed block
#define ASTR  72    // fit LDS tile row stride (bf16): 144B rows, 16B-aligned, 2-way banks

typedef __attribute__((ext_vector_type(8))) short bf16x8;
typedef __attribute__((ext_vector_type(4))) float f32x4;

__device__ __forceinline__ float fast_tanh(float x){
    float e = __expf(2.0f * x);
    float r = __fdividef(1.0f, e + 1.0f);
    return fmaf(-2.0f, r, 1.0f);
}

__device__ __forceinline__ unsigned short f2bf(float x){
    __hip_bfloat16 h = __float2bfloat16(x);
    return *reinterpret_cast<unsigned short*>(&h);
}

__device__ __forceinline__ float bf2f(unsigned short u){
    unsigned int v = ((unsigned int)u) << 16;
    return *reinterpret_cast<float*>(&v);
}

__device__ __forceinline__ unsigned int pack2(float a, float b){
    return (unsigned int)f2bf(a) | ((unsigned int)f2bf(b) << 16);
}

// ---------------- partition atoms by type (deterministic) ----------------
__global__ __launch_bounds__(256) void part_kernel(const int* __restrict__ tmap,
                                                   int* __restrict__ idx,
                                                   int* __restrict__ counts){
    __shared__ int s0[256], s1[256];
    const int tid = threadIdx.x;
    int ty[4]; int c0 = 0, c1 = 0;
    #pragma unroll
    for (int r = 0; r < 4; ++r){
        ty[r] = tmap[tid*4 + r];
        if (ty[r] == 0) c0++; else c1++;
    }
    s0[tid] = c0; s1[tid] = c1;
    __syncthreads();
    for (int off = 1; off < 256; off <<= 1){
        int v0 = (tid >= off) ? s0[tid-off] : 0;
        int v1 = (tid >= off) ? s1[tid-off] : 0;
        __syncthreads();
        s0[tid] += v0; s1[tid] += v1;
        __syncthreads();
    }
    int e0 = s0[tid] - c0, e1 = s1[tid] - c1;
    #pragma unroll
    for (int r = 0; r < 4; ++r){
        int n = tid*4 + r;
        if (ty[r] == 0) idx[e0++] = n; else idx[NATC + e1++] = n;
    }
    if (tid == 255){ counts[0] = s0[255]; counts[1] = s1[255]; }
}

// ------- tiled transpose: src fp32 [2][K][N] -> dst bf16 [2][Npad][Kpad], zero-padded -------
__global__ __launch_bounds__(256) void transp_kernel(const float* __restrict__ src,
                                                     unsigned short* __restrict__ dst,
                                                     int K, int N, int Npad, int Kpad,
                                                     int nkt, int nnt){
    __shared__ float tile[64][65];
    const int tid = threadIdx.x;
    int bid = blockIdx.x;
    const int t  = bid / (nkt*nnt);
    bid -= t*nkt*nnt;
    const int kt = bid / nnt;
    const int nt = bid - kt*nnt;
    const float* s = src + (size_t)t*K*N;
    unsigned short* d = dst + (size_t)t*Npad*Kpad;

    const int c  = tid & 63;
    const int rg = tid >> 6;
    #pragma unroll
    for (int p = 0; p < 16; ++p){
        int row = p*4 + rg;
        int gr = kt*64 + row, gc = nt*64 + c;
        tile[row][c] = (gr < K && gc < N) ? s[(size_t)gr*N + gc] : 0.0f;
    }
    __syncthreads();
    const int nn0 = tid >> 3;
    const int k8  = (tid & 7) * 8;
    #pragma unroll
    for (int p = 0; p < 2; ++p){
        int nn = p*32 + nn0;
        int gn = nt*64 + nn;
        int gk = kt*64 + k8;
        if (gn < Npad && gk < Kpad){
            unsigned short v[8];
            #pragma unroll
            for (int j = 0; j < 8; ++j) v[j] = f2bf(tile[k8+j][nn]);
            *(bf16x8*)(d + (size_t)gn*Kpad + gk) = *(bf16x8*)v;
        }
    }
}

// ---------------- small prep: type features + L0 fold Tb + ew1t + ew2t ----------------
__global__ __launch_bounds__(256) void prep_kernel(const float* __restrict__ tv,
                                                   const float* __restrict__ tW0,
                                                   const float* __restrict__ tb0,
                                                   const float* __restrict__ eW0,
                                                   const float* __restrict__ eb0,
                                                   const float* __restrict__ eW1,
                                                   const float* __restrict__ eW2,
                                                   unsigned short* __restrict__ ew1t,
                                                   unsigned short* __restrict__ ew2t,
                                                   float* __restrict__ Tb){
    __shared__ float tfl[16];
    const int tid = threadIdx.x;
    if (tid < 16){
        int t = tid >> 3, f = tid & 7;
        float s = tb0[f];
        #pragma unroll
        for (int p = 0; p < 4; ++p) s = fmaf(tv[t*4+p], tW0[p*8+f], s);
        tfl[tid] = fast_tanh(s) + tv[t*4 + (f & 3)];
    }
    __syncthreads();
    if (tid < 64){
        int t = tid >> 5, o = tid & 31;
        if (o < 25){
            float s = eb0[o];
            #pragma unroll
            for (int k = 0; k < 8; ++k) s = fmaf(tfl[t*8 + k], eW0[(k+1)*25 + o], s);
            Tb[t*32 + o] = s;
        } else {
            Tb[t*32 + o] = 0.0f;
        }
    }
    for (int i = tid; i < 112*64; i += 256){
        int n = i >> 6, k = i & 63;
        ew2t[i] = (n < M1C && k < 50) ? f2bf(eW2[(size_t)k*M1C + n]) : (unsigned short)0;
    }
    for (int i = tid; i < 64*32; i += 256){
        int n = i >> 5, k = i & 31;
        ew1t[i] = (n < 50 && k < 25) ? f2bf(eW1[(size_t)k*50 + n]) : (unsigned short)0;
    }
}

// ---- embedding (split): each block = (atom a, neighbor-half jh), 128 rows ----
__global__ __launch_bounds__(256, 4) void embed_kernel(
    const float4* __restrict__ imdr,
    const float4* __restrict__ davg,
    const float4* __restrict__ dstd,
    const int*    __restrict__ tmap,
    const float*  __restrict__ eW0,
    const float*  __restrict__ Tb,
    const float*  __restrict__ eb1,
    const float*  __restrict__ eb2,
    const unsigned short* __restrict__ ew1t,
    const unsigned short* __restrict__ ew2t,
    float* __restrict__ xyzg)        // [4096][2][448]
{
    __shared__ __align__(16) float Rif[NR][4];
    __shared__ __align__(16) unsigned short H1s[NR][H1STR];
    __shared__ __align__(16) unsigned short H2s[NR][H2STR];

    const int tid = threadIdx.x;
    const int bid = blockIdx.x;
    const int a   = bid >> 1;
    const int jh  = bid & 1;
    const int n0  = a & (NATC - 1);
    const int itype = tmap[n0];

    if (tid < NR){
        const int jg = jh*NR + tid;
        unsigned int* rowp = (unsigned int*)&H1s[tid][0];
        if (jg < MNTC){
            float4 dr = imdr[(size_t)a*MNTC + jg];
            float r  = dr.x;
            float rs = (r > 1e-5f) ? r : 1.0f;
            float ir = __fdividef(1.0f, rs);
            float u  = (r - 0.5f) * (1.0f/5.5f);
            float u2 = u*u, u3 = u2*u;
            float smid = ir * (u3 * (-6.0f*u2 + 15.0f*u - 10.0f) + 1.0f);
            float S = 0.0f;
            if (r > 0.0f && r < 0.5f)       S = ir;
            else if (r >= 0.5f && r < 6.0f) S = smid;
            bool msk = fabsf(r) > 1e-5f;
            float R0 = S;
            float R1 = msk ? S * dr.y * ir : 0.0f;
            float R2 = msk ? S * dr.z * ir : 0.0f;
            float R3 = msk ? S * dr.w * ir : 0.0f;
            float4 av = davg[itype*MNTC + jg];
            float4 sv = dstd[itype*MNTC + jg];
            float rin0 = __fdividef(R0 - av.x, sv.x);
            float rin1 = __fdividef(R1 - av.y, sv.y);
            float rin2 = __fdividef(R2 - av.z, sv.z);
            float rin3 = __fdividef(R3 - av.w, sv.w);
            Rif[tid][0] = rin0; Rif[tid][1] = rin1; Rif[tid][2] = rin2; Rif[tid][3] = rin3;

            const float* tb = Tb + ((jg >= 100) ? 32 : 0);
            float h1[25];
            #pragma unroll
            for (int o = 0; o < 25; ++o)
                h1[o] = fast_tanh(fmaf(rin0, eW0[o], tb[o]));

            #pragma unroll
            for (int c = 0; c < 12; ++c) rowp[c] = pack2(h1[2*c], h1[2*c+1]);
            rowp[12] = (unsigned int)f2bf(h1[24]);
            #pragma unroll
            for (int c = 13; c < 20; ++c) rowp[c] = 0u;
        } else {
            Rif[tid][0] = 0.0f; Rif[tid][1] = 0.0f; Rif[tid][2] = 0.0f; Rif[tid][3] = 0.0f;
            #pragma unroll
            for (int c = 0; c < 20; ++c) rowp[c] = 0u;
        }
    }
    __syncthreads();

    const int lane = tid & 63;
    const int w    = tid >> 6;
    const int lc   = lane & 15;
    const int lg   = lane >> 4;

    // L1 via MFMA: M=128, K=32(pad25), N=64(pad50)
    #pragma unroll
    for (int mi = 0; mi < 2; ++mi){
        const int mt = w + mi*4;
        bf16x8 af = *(const bf16x8*)&H1s[mt*16 + lc][lg*8];
        const int rbase = mt*16 + lg*4;
        #pragma unroll
        for (int nt = 0; nt < 4; ++nt){
            const int n = nt*16 + lc;
            const bool live = (n < 50);
            float bv = live ? eb1[n] : 0.0f;
            f32x4 c;
            c[0] = bv; c[1] = bv; c[2] = bv; c[3] = bv;
            bf16x8 bfr = *(const bf16x8*)(ew1t + n*32 + lg*8);
            c = __builtin_amdgcn_mfma_f32_16x16x32_bf16(af, bfr, c, 0, 0, 0);
            const int rc = n % 25;
            #pragma unroll
            for (int i = 0; i < 4; ++i){
                const int row = rbase + i;
                unsigned short v = 0;
                if (live) v = f2bf(fast_tanh(c[i]) + bf2f(H1s[row][rc]));
                H2s[row][n] = v;
            }
        }
    }
    __syncthreads();

    // L2 via MFMA (M=128, K=64, N=112) + xyz reduce, two N-halves
    float* xyzp = (float*)&H1s[0][0];        // [4][4][112] overlay

    #pragma unroll
    for (int half = 0; half < 2; ++half){
        const int ntbase = half * 4;
        float xacc[4][4];
        #pragma unroll
        for (int q = 0; q < 4; ++q)
            #pragma unroll
            for (int d = 0; d < 4; ++d) xacc[q][d] = 0.0f;

        #pragma unroll
        for (int mi = 0; mi < 2; ++mi){
            const int mt = w + mi*4;
            const int rbase = mt*16 + lg*4;
            float4 rj[4];
            #pragma unroll
            for (int i = 0; i < 4; ++i) rj[i] = *(const float4*)&Rif[rbase + i][0];
            const unsigned short* arow = &H2s[mt*16 + lc][0];
            bf16x8 a0 = *(const bf16x8*)(arow + lg*8);
            bf16x8 a1 = *(const bf16x8*)(arow + 32 + lg*8);
            #pragma unroll
            for (int q = 0; q < 4; ++q){
                const int nt = ntbase + q;
                if (nt >= 7) continue;
                const int cg = nt*16 + lc;
                const unsigned short* bp = ew2t + (size_t)cg*64 + lg*8;
                bf16x8 b0 = *(const bf16x8*)(bp);
                bf16x8 b1 = *(const bf16x8*)(bp + 32);
                float bv = (cg < M1C) ? eb2[cg] : 0.0f;
                f32x4 c;
                c[0] = bv; c[1] = bv; c[2] = bv; c[3] = bv;
                c = __builtin_amdgcn_mfma_f32_16x16x32_bf16(a0, b0, c, 0, 0, 0);
                c = __builtin_amdgcn_mfma_f32_16x16x32_bf16(a1, b1, c, 0, 0, 0);
                const int rc = (cg >= 100) ? cg - 100 : ((cg >= 50) ? cg - 50 : cg);
                #pragma unroll
                for (int i = 0; i < 4; ++i){
                    float g = fast_tanh(c[i]) + bf2f(H2s[rbase + i][rc]);
                    xacc[q][0] = fmaf(g, rj[i].x, xacc[q][0]);
                    xacc[q][1] = fmaf(g, rj[i].y, xacc[q][1]);
                    xacc[q][2] = fmaf(g, rj[i].z, xacc[q][2]);
                    xacc[q][3] = fmaf(g, rj[i].w, xacc[q][3]);
                }
            }
        }
        #pragma unroll
        for (int q = 0; q < 4; ++q){
            const int nt = ntbase + q;
            if (nt >= 7) continue;
            #pragma unroll
            for (int d = 0; d < 4; ++d){
                float v = xacc[q][d];
                v += __shfl_xor(v, 16);
                v += __shfl_xor(v, 32);
                if (lane < 16) xyzp[((w*4 + d)*112) + nt*16 + lc] = v;
            }
        }
    }
    __syncthreads();

    for (int i = tid; i < 448; i += 256){
        int d = i / 112, m = i - d*112;
        xyzg[(size_t)a*896 + jh*448 + i] =
            xyzp[(0*4+d)*112 + m] + xyzp[(1*4+d)*112 + m] +
            xyzp[(2*4+d)*112 + m] + xyzp[(3*4+d)*112 + m];
    }
}

// ---------------- DR: combine halves, DR = xyz^T @ xyz[:, :16] -> bf16 ----------------
__global__ __launch_bounds__(256) void dr_kernel(const float* __restrict__ xyzg,
                                                 unsigned short* __restrict__ DRout){
    __shared__ float xyzs[448];
    const int a = blockIdx.x;
    const int tid = threadIdx.x;
    for (int i = tid; i < 448; i += 256)
        xyzs[i] = (xyzg[(size_t)a*896 + i] + xyzg[(size_t)a*896 + 448 + i]) * (1.0f / (float)MNTC);
    __syncthreads();
    if (tid < 200){
        const int i8 = tid * 8;
        const int m  = i8 >> 4;
        const int qb = i8 & 15;
        float xm[4], s[8];
        #pragma unroll
        for (int d = 0; d < 4; ++d) xm[d] = xyzs[d*112 + m];
        #pragma unroll
        for (int e = 0; e < 8; ++e){
            float acc = 0.0f;
            #pragma unroll
            for (int d = 0; d < 4; ++d) acc = fmaf(xm[d], xyzs[d*112 + qb + e], acc);
            s[e] = acc;
        }
        unsigned short v[8];
        #pragma unroll
        for (int e = 0; e < 8; ++e) v[e] = f2bf(s[e]);
        *(bf16x8*)(DRout + (size_t)a*(M1C*M2C) + i8) = *(bf16x8*)v;
    }
}

// ---------------- fit L0: tiled GEMM, M=64(atom-gather) x N=64, K=1600 ----------------
// grid: bid = ((b*2 + t)*16 + mt)*4 + ntile ; h0 rows R = (b*2+t)*1024 + mbase + row
__global__ __launch_bounds__(256, 4) void fit_l0(
    const unsigned short* __restrict__ DRbf,   // [4096][1600] bf16
    const int*   __restrict__ idx,
    const int*   __restrict__ counts,
    const unsigned short* __restrict__ w0p,    // [2][256][1600], cols 240..255 zero
    const float* __restrict__ fb0,
    unsigned short* __restrict__ h0)           // [8192][256]
{
    int bid = blockIdx.x;
    const int ntile = bid & 3; bid >>= 2;
    const int mt = bid & 15;  bid >>= 4;
    const int t = bid & 1;
    const int b = bid >> 1;
    const int cnt = counts[t];
    const int mbase = mt*64;
    if (mbase >= cnt) return;

    __shared__ int ns[64];
    __shared__ __align__(16) unsigned short As[64][ASTR];
    __shared__ __align__(16) unsigned short Bs[64][ASTR];

    const int tid = threadIdx.x;
    if (tid < 64) ns[tid] = idx[t*NATC + min(mbase + tid, cnt - 1)];
    __syncthreads();

    const int lane = tid & 63, w = tid >> 6;
    const int wm = w >> 1, wn = w & 1;
    const int lc = lane & 15, lg = lane >> 4;

    const int srow = tid >> 3;            // 0..31
    const int scol = (tid & 7) * 8;       // 0..56

    const unsigned short* arow0 = DRbf + ((size_t)(b*NATC + ns[srow]))*1600;
    const unsigned short* arow1 = DRbf + ((size_t)(b*NATC + ns[srow + 32]))*1600;
    const unsigned short* brow0 = w0p + ((size_t)(t*NPAD + ntile*64 + srow))*1600;
    const unsigned short* brow1 = w0p + ((size_t)(t*NPAD + ntile*64 + srow + 32))*1600;

    // acc init with bias (per-column, shared by the 4 row-elems of the frag)
    f32x4 acc[2][2];
    #pragma unroll
    for (int mi = 0; mi < 2; ++mi)
        #pragma unroll
        for (int ni = 0; ni < 2; ++ni){
            int col = ntile*64 + wn*32 + ni*16 + lc;
            float bv = (col < FHC) ? fb0[t*FHC + col] : 0.0f;
            acc[mi][ni][0] = bv; acc[mi][ni][1] = bv;
            acc[mi][ni][2] = bv; acc[mi][ni][3] = bv;
        }

    for (int kc = 0; kc < 1600; kc += 64){
        __syncthreads();
        *(bf16x8*)&As[srow][scol]      = *(const bf16x8*)(arow0 + kc + scol);
        *(bf16x8*)&As[srow + 32][scol] = *(const bf16x8*)(arow1 + kc + scol);
        *(bf16x8*)&Bs[srow][scol]      = *(const bf16x8*)(brow0 + kc + scol);
        *(bf16x8*)&Bs[srow + 32][scol] = *(const bf16x8*)(brow1 + kc + scol);
        __syncthreads();
        #pragma unroll
        for (int kk = 0; kk < 2; ++kk){
            bf16x8 a0 = *(const bf16x8*)&As[wm*32 + lc][kk*32 + lg*8];
            bf16x8 a1 = *(const bf16x8*)&As[wm*32 + 16 + lc][kk*32 + lg*8];
            bf16x8 b0 = *(const bf16x8*)&Bs[wn*32 + lc][kk*32 + lg*8];
            bf16x8 b1 = *(const bf16x8*)&Bs[wn*32 + 16 + lc][kk*32 + lg*8];
            acc[0][0] = __builtin_amdgcn_mfma_f32_16x16x32_bf16(a0, b0, acc[0][0], 0, 0, 0);
            acc[0][1] = __builtin_amdgcn_mfma_f32_16x16x32_bf16(a0, b1, acc[0][1], 0, 0, 0);
            acc[1][0] = __builtin_amdgcn_mfma_f32_16x16x32_bf16(a1, b0, acc[1][0], 0, 0, 0);
            acc[1][1] = __builtin_amdgcn_mfma_f32_16x16x32_bf16(a1, b1, acc[1][1], 0, 0, 0);
        }
    }

    const size_t Rseg = (size_t)((b*2 + t)*1024 + mbase);
    #pragma unroll
    for (int mi = 0; mi < 2; ++mi)
        #pragma unroll
        for (int ni = 0; ni < 2; ++ni){
            int col = ntile*64 + wn*32 + ni*16 + lc;
            #pragma unroll
            for (int i = 0; i < 4; ++i){
                int rowl = wm*32 + mi*16 + lg*4 + i;
                h0[(Rseg + rowl)*NPAD + col] = f2bf(fast_tanh(acc[mi][ni][i]));
            }
        }
}

// ------- fit L1/L2: tiled GEMM M=64 x N=64, K=256; resnet; optional fused final dot -------
__global__ __launch_bounds__(256, 4) void fit_l12(
    const unsigned short* __restrict__ h_in,   // [8192][256]
    const int*   __restrict__ counts,
    const unsigned short* __restrict__ wp,     // [2][256][256]
    const float* __restrict__ fb,
    const float* __restrict__ wf,              // null -> write h_out; else fuse final dot
    unsigned short* __restrict__ h_out,        // [8192][256]
    float* __restrict__ Ei_buf)                // [8192]
{
    int bid = blockIdx.x;
    const int ntile = bid & 3; bid >>= 2;
    const int mt = bid & 15;  bid >>= 4;
    const int t = bid & 1;
    const int b = bid >> 1;
    const int cnt = counts[t];
    const int mbase = mt*64;
    if (mbase >= cnt) return;

    __shared__ __align__(16) unsigned short As[64][ASTR];
    __shared__ __align__(16) unsigned short Bs[64][ASTR];

    const int tid = threadIdx.x;
    const int lane = tid & 63, w = tid >> 6;
    const int wm = w >> 1, wn = w & 1;
    const int lc = lane & 15, lg = lane >> 4;

    const int srow = tid >> 3;
    const int scol = (tid & 7) * 8;

    const size_t Rseg = (size_t)((b*2 + t)*1024 + mbase);
    const unsigned short* arow0 = h_in + (Rseg + srow)*NPAD;
    const unsigned short* arow1 = h_in + (Rseg + srow + 32)*NPAD;
    const unsigned short* brow0 = wp + ((size_t)(t*NPAD + ntile*64 + srow))*NPAD;
    const unsigned short* brow1 = wp + ((size_t)(t*NPAD + ntile*64 + srow + 32))*NPAD;

    f32x4 acc[2][2];
    #pragma unroll
    for (int mi = 0; mi < 2; ++mi)
        #pragma unroll
        for (int ni = 0; ni < 2; ++ni){
            int col = ntile*64 + wn*32 + ni*16 + lc;
            float bv = (col < FHC) ? fb[t*FHC + col] : 0.0f;
            acc[mi][ni][0] = bv; acc[mi][ni][1] = bv;
            acc[mi][ni][2] = bv; acc[mi][ni][3] = bv;
        }

    for (int kc = 0; kc < 256; kc += 64){
        __syncthreads();
        *(bf16x8*)&As[srow][scol]      = *(const bf16x8*)(arow0 + kc + scol);
        *(bf16x8*)&As[srow + 32][scol] = *(const bf16x8*)(arow1 + kc + scol);
        *(bf16x8*)&Bs[srow][scol]      = *(const bf16x8*)(brow0 + kc + scol);
        *(bf16x8*)&Bs[srow + 32][scol] = *(const bf16x8*)(brow1 + kc + scol);
        __syncthreads();
        #pragma unroll
        for (int kk = 0; kk < 2; ++kk){
            bf16x8 a0 = *(const bf16x8*)&As[wm*32 + lc][kk*32 + lg*8];
            bf16x8 a1 = *(const bf16x8*)&As[wm*32 + 16 + lc][kk*32 + lg*8];
            bf16x8 b0 = *(const bf16x8*)&Bs[wn*32 + lc][kk*32 + lg*8];
            bf16x8 b1 = *(const bf16x8*)&Bs[wn*32 + 16 + lc][kk*32 + lg*8];
            acc[0][0] = __builtin_amdgcn_mfma_f32_16x16x32_bf16(a0, b0, acc[0][0], 0, 0, 0);
            acc[0][1] = __builtin_amdgcn_mfma_f32_16x16x32_bf16(a0, b1, acc[0][1], 0, 0, 0);
            acc[1][0] = __builtin_amdgcn_mfma_f32_16x16x32_bf16(a1, b0, acc[1][0], 0, 0, 0);
            acc[1][1] = __builtin_amdgcn_mfma_f32_16x16x32_bf16(a1, b1, acc[1][1], 0, 0, 0);
        }
    }

    const bool fuse = (wf != nullptr);
    #pragma unroll
    for (int mi = 0; mi < 2; ++mi){
        float pr[4] = {0.0f, 0.0f, 0.0f, 0.0f};
        #pragma unroll
        for (int ni = 0; ni < 2; ++ni){
            int col = ntile*64 + wn*32 + ni*16 + lc;
            float wfv = 0.0f;
            if (fuse) wfv = (col < FHC) ? wf[t*FHC + col] : 0.0f;
            #pragma unroll
            for (int i = 0; i < 4; ++i){
                int rowl = wm*32 + mi*16 + lg*4 + i;
                size_t gaddr = (Rseg + rowl)*NPAD + col;
                float hv = fast_tanh(acc[mi][ni][i]) + bf2f(h_in[gaddr]);
                if (!fuse) h_out[gaddr] = f2bf(hv);
                else       pr[i] = fmaf(hv, wfv, pr[i]);
            }
        }
        if (fuse){
            #pragma unroll
            for (int i = 0; i < 4; ++i){
                float v = pr[i];
                v += __shfl_xor(v, 1); v += __shfl_xor(v, 2);
                v += __shfl_xor(v, 4); v += __shfl_xor(v, 8);
                if (lc == 0){
                    int rowl = wm*32 + mi*16 + lg*4 + i;
                    atomicAdd(&Ei_buf[Rseg + rowl], v);
                }
            }
        }
    }
}

// ---------------- finish: Ei scatter + Etot ----------------
__global__ __launch_bounds__(256) void finish_kernel(const float* __restrict__ Ei_buf,
                                                     const int* __restrict__ idx,
                                                     const int* __restrict__ counts,
                                                     const float* __restrict__ fbf,
                                                     float* __restrict__ out){
    const int gid = blockIdx.x*256 + threadIdx.x;   // 0..8191
    const int b = gid >> 11;
    const int t = (gid >> 10) & 1;
    const int k = gid & 1023;
    float e = 0.0f;
    if (k < counts[t]){
        e = Ei_buf[gid] + fbf[t];
        out[4 + b*NATC + idx[t*NATC + k]] = e;
    }
    #pragma unroll
    for (int off = 1; off < 64; off <<= 1) e += __shfl_xor(e, off);
    if ((threadIdx.x & 63) == 0) atomicAdd(&out[b], e);
}

extern "C" void kernel_launch(void* const* d_in, const int* in_sizes, int n_in,
                              void* d_out, int out_size, void* d_ws, size_t ws_size,
                              hipStream_t stream)
{
    (void)in_sizes; (void)n_in; (void)out_size; (void)ws_size;
    const int*   tmap = (const int*)d_in[1];
    const float* imdr = (const float*)d_in[3];
    const float* davg = (const float*)d_in[5];
    const float* dstd = (const float*)d_in[6];
    const float* tv   = (const float*)d_in[7];
    const float* tW0  = (const float*)d_in[8];
    const float* tb0  = (const float*)d_in[9];
    const float* eW0  = (const float*)d_in[10];
    const float* eb0  = (const float*)d_in[11];
    const float* eW1  = (const float*)d_in[12];
    const float* eb1  = (const float*)d_in[13];
    const float* eW2  = (const float*)d_in[14];
    const float* eb2  = (const float*)d_in[15];
    const float* fW0  = (const float*)d_in[16];
    const float* fb0  = (const float*)d_in[17];
    const float* fW1  = (const float*)d_in[18];
    const float* fb1  = (const float*)d_in[19];
    const float* fW2  = (const float*)d_in[20];
    const float* fb2  = (const float*)d_in[21];
    const float* fWf  = (const float*)d_in[22];
    const float* fbf  = (const float*)d_in[23];
    float* out = (float*)d_out;

    char* ws = (char*)d_ws;
    int*   counts = (int*)ws;
    int*   idx    = (int*)(ws + 64);
    unsigned short* DRbf = (unsigned short*)(ws + 16384);                 // 13,107,200 B
    unsigned short* w0p  = DRbf + (size_t)BATCH*NATC*1600;                // 1,638,400 B
    unsigned short* w1p  = w0p + (size_t)2*NPAD*1600;                     //   262,144 B
    unsigned short* w2p  = w1p + (size_t)2*NPAD*NPAD;                     //   262,144 B
    unsigned short* ew2t = w2p + (size_t)2*NPAD*NPAD;                     //    14,336 B
    unsigned short* ew1t = ew2t + 112*64;                                 //     4,096 B
    float* Tb            = (float*)(ew1t + 64*32);                        //     4,096 B (256 used)
    float* xyzg          = (float*)((char*)Tb + 4096);                    // 14,680,064 B
    unsigned short* h0   = (unsigned short*)(xyzg + (size_t)BATCH*NATC*896); // 4,194,304 B
    unsigned short* h1   = h0 + (size_t)8192*NPAD;                        // 4,194,304 B
    float* Ei_buf        = (float*)(h1 + (size_t)8192*NPAD);              //    32,768 B

    hipMemsetAsync(d_out, 0, 4*sizeof(float), stream);
    hipMemsetAsync(Ei_buf, 0, 8192*sizeof(float), stream);
    part_kernel<<<1, 256, 0, stream>>>(tmap, idx, counts);
    prep_kernel<<<1, 256, 0, stream>>>(tv, tW0, tb0, eW0, eb0, eW1, eW2, ew1t, ew2t, Tb);
    transp_kernel<<<2*25*4, 256, 0, stream>>>(fW0, w0p, 1600, FHC, NPAD, 1600, 25, 4);
    transp_kernel<<<2*4*4,  256, 0, stream>>>(fW1, w1p, FHC, FHC, NPAD, NPAD, 4, 4);
    transp_kernel<<<2*4*4,  256, 0, stream>>>(fW2, w2p, FHC, FHC, NPAD, NPAD, 4, 4);
    embed_kernel<<<2*BATCH*NATC, 256, 0, stream>>>(
        (const float4*)imdr, (const float4*)davg, (const float4*)dstd, tmap,
        eW0, Tb, eb1, eb2, ew1t, ew2t, xyzg);
    dr_kernel<<<BATCH*NATC, 256, 0, stream>>>(xyzg, DRbf);
    fit_l0<<<BATCH*2*16*4, 256, 0, stream>>>(DRbf, idx, counts, w0p, fb0, h0);
    fit_l12<<<BATCH*2*16*4, 256, 0, stream>>>(h0, counts, w1p, fb1, nullptr, h1, Ei_buf);
    fit_l12<<<BATCH*2*16*4, 256, 0, stream>>>(h1, counts, w2p, fb2, fWf, h0, Ei_buf);
    finish_kernel<<<32, 256, 0, stream>>>(Ei_buf, idx, counts, fbf, out);
}